// Round 18
// baseline (386.862 us; speedup 1.0000x reference)
//
#include <hip/hip_runtime.h>
#include <hip/hip_bf16.h>

// Problem constants (B=4, S=4096, D=4096, r=4, COFF=2, HD=512)
#define D_DIM 4096
#define OD    1024          // COFF*HD combined projection width
#define M_TOT 16384         // B*S
#define N_TOT 2048          // 2*OD (kv/gate interleaved)
#define BM 256
#define BN 256
#define BK 64

#define GLOBAL_AS __attribute__((address_space(1)))
#define LDS_AS    __attribute__((address_space(3)))

typedef __attribute__((ext_vector_type(8))) short          bf16x8;
typedef __attribute__((ext_vector_type(8))) unsigned short u16x8;
typedef __attribute__((ext_vector_type(4))) float          f32x4;

__device__ __forceinline__ unsigned short f2bf(float f) {
    unsigned int u = __float_as_uint(f);
    u = (u + 0x7fffu + ((u >> 16) & 1u)) >> 16;
    return (unsigned short)u;
}

__device__ __forceinline__ float sigm(float x) {
    return 1.0f / (1.0f + __expf(-x));
}

__device__ __forceinline__ void gload16(const void* g, void* l) {
    __builtin_amdgcn_global_load_lds((const GLOBAL_AS void*)g, (LDS_AS void*)l, 16, 0, 0);
}

// ---- prep: interleave wkv/wgate rows into combined bf16 weight [2048][4096]
__global__ void prep_weights(const float* __restrict__ wkv,
                             const float* __restrict__ wgate,
                             unsigned short* __restrict__ Wc) {
    int t  = blockIdx.x * 256 + threadIdx.x;
    int n  = t >> 9;
    int k8 = t & 511;
    const float* src = (n & 1) ? wgate : wkv;
    const float4* s4 = (const float4*)(src + (size_t)(n >> 1) * D_DIM + k8 * 8);
    float4 a = s4[0], b = s4[1];
    u16x8 o;
    o[0] = f2bf(a.x); o[1] = f2bf(a.y); o[2] = f2bf(a.z); o[3] = f2bf(a.w);
    o[4] = f2bf(b.x); o[5] = f2bf(b.y); o[6] = f2bf(b.z); o[7] = f2bf(b.w);
    *(u16x8*)(Wc + (size_t)n * D_DIM + k8 * 8) = o;
}

// ---- prep: ape mean over the 4 window positions
__global__ void prep_ape(const float* __restrict__ ape, float* __restrict__ am) {
    int t = blockIdx.x * 256 + threadIdx.x;
    if (t < OD)
        am[t] = 0.25f * (ape[t] + ape[OD + t] + ape[2 * OD + t] + ape[3 * OD + t]);
}

// =====================================================================
// 256x256 / BK=64 / 8-wave GEMM, r17 schedule (4 merged intervals,
// chain (0,0)->(0,1)->(1,1)->(1,0)) with the fp32->bf16 conversion of
// A FUSED into staging (prep_x kernel eliminated, -64us serial,
// -128MB HBM):
//   A staged by reg-path: interval Pk ISSUES 4 float4 loads of an
//   A-half-unit (fp32, pre-swizzled col-chunk sc8), interval Pk+1
//   vmcnt-drains, converts (RNE f2bf), ds_write_b128 into the SAME
//   linear LDS layout as the old gload path (reads unchanged).
//   B stays gload_lds (pre-swizzled source).
// Issue map / FIFO (every interval ends vmcnt(own-issue-count), which
// drains ALL older loads -> order-robust):
//   P1 (8): buf1.A0^f + buf1.{B0,B1}^g @kb1 ; writes buf0.A1 (prev-P4)
//   P2 (4): buf1.A1^f @kb1              ; writes buf1.A0
//   P3 (8): buf0'.A0^f + buf0'.{B0,B1}^g @kna ; writes buf1.A1
//   P4 (4): buf0'.A1^f @kna             ; writes buf0'.A0
// Every write lands >=1 barrier after its region's last read and >=1
// barrier before its first read; ds_writes fenced by lgkmcnt(0)+BAR.
// Cross-barrier regs: one A-frag (16) + B1 carry (16) = 32 (<=48 safe).
// =====================================================================
extern __shared__ __align__(16) unsigned short smem_u16[];

struct AFrag { float4 v0, v1, v2, v3; };

__global__ __launch_bounds__(512, 2)
void gemm_fused_8ph(const float* __restrict__ X,
                    const unsigned short* __restrict__ Wc,
                    const float* __restrict__ ape_mean,
                    float* __restrict__ out_pooled) {
    unsigned short* Asb[2] = {smem_u16,               smem_u16 + BM * BK};
    unsigned short* Bsb[2] = {smem_u16 + 2 * BM * BK, smem_u16 + 3 * BM * BK};

    const int tid  = threadIdx.x;
    const int lane = tid & 63;
    const int wave = tid >> 6;          // 8 waves: wm = wave>>2 (2), wn = wave&3 (4)
    const int wm   = wave >> 2;
    const int wn   = wave & 3;
    const int h    = lane & 15;
    const int q    = lane >> 4;

    // XCD partition by m: xcd = bid&7 owns m-tiles [xcd*8, xcd*8+8), all 8 n-tiles.
    const int bid = blockIdx.x;
    const int j   = bid >> 3;
    const int m0  = ((bid & 7) * 8 + (j >> 3)) * BM;
    const int n0  = (j & 7) * BN;

    // pre-swizzled source chunk (rule 21 both-sides; verified r3)
    const int sc8 = (lane & 7) ^ ((lane >> 3) & 7);
    const float*          Af = X  + (size_t)(m0 + wave * 8 + (lane >> 3)) * D_DIM + sc8 * 8;
    const unsigned short* Bg = Wc + (size_t)(n0 + (wave & 3) * 8 + (lane >> 3)) * D_DIM + sc8 * 8;
    const int bstripe = wave >> 2;      // waves 0-3: stripes {0,2}; 4-7: {1,3}

    // Precomputed LDS read bases (elements, r13): addr = (W + f*16 + h)*64
    //   + ((ks*32 + q*8) ^ ((h&7)<<3)), frag step f*1024.
    const int xorv = (h & 7) << 3;
    const unsigned aoff0 = (unsigned)((wm * 128 + h) * 64);
    const unsigned boff0 = (unsigned)((wn * 64 + h) * 64);
    const unsigned short* aB[2][2];   // [buf][ks]
    const unsigned short* bB[2][2];
#pragma unroll
    for (int b = 0; b < 2; ++b)
#pragma unroll
        for (int ks = 0; ks < 2; ++ks) {
            const unsigned swz = (unsigned)((ks * 32 + q * 8) ^ xorv);
            aB[b][ks] = Asb[b] + aoff0 + swz;
            bB[b][ks] = Bsb[b] + boff0 + swz;
        }

    // A write targets (linear, identical to old gload dest): lane chunk = lane*8 elems
    unsigned short* AsW0 = Asb[0] + (wave * 8) * BK + lane * 8;
    unsigned short* AsW1 = Asb[1] + (wave * 8) * BK + lane * 8;

#define AISSUE(frag, kofs, half)                                                   \
    do {                                                                           \
        const float* p0_ = Af + (size_t)((half) * 64) * D_DIM + (kofs);            \
        frag.v0 = *(const float4*)(p0_);                                           \
        frag.v1 = *(const float4*)(p0_ + 4);                                       \
        frag.v2 = *(const float4*)(p0_ + (size_t)128 * D_DIM);                     \
        frag.v3 = *(const float4*)(p0_ + (size_t)128 * D_DIM + 4);                 \
    } while (0)

#define AWRITE(buf, half, frag)                                                    \
    do {                                                                           \
        u16x8 w0_, w1_;                                                            \
        w0_[0] = f2bf(frag.v0.x); w0_[1] = f2bf(frag.v0.y);                        \
        w0_[2] = f2bf(frag.v0.z); w0_[3] = f2bf(frag.v0.w);                        \
        w0_[4] = f2bf(frag.v1.x); w0_[5] = f2bf(frag.v1.y);                        \
        w0_[6] = f2bf(frag.v1.z); w0_[7] = f2bf(frag.v1.w);                        \
        w1_[0] = f2bf(frag.v2.x); w1_[1] = f2bf(frag.v2.y);                        \
        w1_[2] = f2bf(frag.v2.z); w1_[3] = f2bf(frag.v2.w);                        \
        w1_[4] = f2bf(frag.v3.x); w1_[5] = f2bf(frag.v3.y);                        \
        w1_[6] = f2bf(frag.v3.z); w1_[7] = f2bf(frag.v3.w);                        \
        unsigned short* d_ = ((buf) ? AsW1 : AsW0) + (half) * 64 * BK;             \
        *(u16x8*)(d_)             = w0_;                                           \
        *(u16x8*)(d_ + 128 * BK)  = w1_;                                           \
    } while (0)

#define STAGE_B(buf, qb, kofs)                                                     \
    do {                                                                           \
        const int r0_ = (qb) * 32 + bstripe * 64;                                  \
        const int r1_ = (qb) * 32 + (2 + bstripe) * 64;                            \
        gload16(Bg + (size_t)r0_ * D_DIM + (kofs),                                 \
                Bsb[buf] + (r0_ + (wave & 3) * 8) * BK);                           \
        gload16(Bg + (size_t)r1_ * D_DIM + (kofs),                                 \
                Bsb[buf] + (r1_ + (wave & 3) * 8) * BK);                           \
    } while (0)

#define LOAD_A(buf, qa, dst)                                                       \
    do {                                                                           \
        _Pragma("unroll")                                                          \
        for (int mi = 0; mi < 4; ++mi)                                             \
            _Pragma("unroll")                                                      \
            for (int ks = 0; ks < 2; ++ks)                                         \
                dst[mi][ks] = *(const bf16x8*)(aB[buf][ks] +                       \
                              ((qa) * 4 + mi) * 1024);                             \
    } while (0)

#define LOAD_B(buf, qb, dst)                                                       \
    do {                                                                           \
        _Pragma("unroll")                                                          \
        for (int ni = 0; ni < 2; ++ni)                                             \
            _Pragma("unroll")                                                      \
            for (int ks = 0; ks < 2; ++ks)                                         \
                dst[ni][ks] = *(const bf16x8*)(bB[buf][ks] +                       \
                              ((qb) * 2 + ni) * 1024);                             \
    } while (0)

#define MFMA_Q(qa, qb, asrc, bsrc)                                                 \
    do {                                                                           \
        __builtin_amdgcn_s_setprio(1);                                             \
        _Pragma("unroll")                                                          \
        for (int mi = 0; mi < 4; ++mi)                                             \
            _Pragma("unroll")                                                      \
            for (int ni = 0; ni < 2; ++ni)                                         \
                _Pragma("unroll")                                                  \
                for (int ks = 0; ks < 2; ++ks)                                     \
                    acc[(qa) * 4 + mi][(qb) * 2 + ni] =                            \
                        __builtin_amdgcn_mfma_f32_16x16x32_bf16(                   \
                            asrc[mi][ks], bsrc[ni][ks],                            \
                            acc[(qa) * 4 + mi][(qb) * 2 + ni], 0, 0, 0);           \
        __builtin_amdgcn_s_setprio(0);                                             \
    } while (0)

#define BAR()   __builtin_amdgcn_s_barrier()
#define VMW(n)  asm volatile("s_waitcnt vmcnt(" #n ")" ::: "memory")
#define LGKM0() asm volatile("s_waitcnt lgkmcnt(0)" ::: "memory")

    f32x4 acc[8][4];
    const f32x4 z = {0.f, 0.f, 0.f, 0.f};
#pragma unroll
    for (int i = 0; i < 8; ++i)
#pragma unroll
        for (int jj = 0; jj < 4; ++jj) acc[i][jj] = z;

    AFrag fa, fb;

    // ---- prologue: buf0.A0 write, buf0.B0/B1 gload, buf0.A1 issued (-> P1)
    AISSUE(fa, 0, 0);
    VMW(0);
    AWRITE(0, 0, fa);
    STAGE_B(0, 0, 0); STAGE_B(0, 1, 0);
    AISSUE(fb, 0, 1);
    VMW(4);          // drain the 2x2 B-gloads; leave fb's 4 fp32 loads
    LGKM0();
    BAR();

    for (int kt2 = 0; kt2 < D_DIM; kt2 += 2 * BK) {
        const int kb1 = kt2 + BK;                // buf1 tile this trip (<= 4032)
        const int kna = (kt2 + 2 * BK) & 4095;   // next buf0 tile (wraps: dead)
        bf16x8 av[4][2], bv[2][2];

        // ---- P1: read buf0 Q(0,0),Q(0,1) ----
        LOAD_A(0, 0, av); LOAD_B(0, 0, bv);
        AISSUE(fa, kb1, 0);                      // buf1.A0 fp32 loads
        STAGE_B(1, 0, kb1); STAGE_B(1, 1, kb1);  // buf1 B0,B1 gloads
        VMW(8);                                  // drain all older (prev-P4's fb)
        AWRITE(0, 1, fb);                        // write buf0.A1 (read in P2)
        MFMA_Q(0, 0, av, bv);
        LOAD_B(0, 1, bv);
        MFMA_Q(0, 1, av, bv);
        LGKM0(); BAR();

        // ---- P2: read buf0 Q(1,1),Q(1,0) ----
        LOAD_A(0, 1, av);
        AISSUE(fb, kb1, 1);                      // buf1.A1 fp32 loads
        VMW(4);                                  // drain P1's 8 (fa + B-gloads)
        AWRITE(1, 0, fa);                        // write buf1.A0 (read in P3)
        MFMA_Q(1, 1, av, bv);
        LOAD_B(0, 0, bv);
        MFMA_Q(1, 0, av, bv);
        LGKM0(); BAR();

        // ---- P3: read buf1 Q(0,0),Q(0,1) ----
        LOAD_A(1, 0, av); LOAD_B(1, 0, bv);
        AISSUE(fa, kna, 0);                      // buf0'.A0 fp32 loads
        STAGE_B(0, 0, kna); STAGE_B(0, 1, kna);  // buf0' B0,B1 gloads
        VMW(8);                                  // drain P2's fb
        AWRITE(1, 1, fb);                        // write buf1.A1 (read in P4)
        MFMA_Q(0, 0, av, bv);
        LOAD_B(1, 1, bv);
        MFMA_Q(0, 1, av, bv);
        LGKM0(); BAR();

        // ---- P4: read buf1 Q(1,1),Q(1,0) ----
        LOAD_A(1, 1, av);
        AISSUE(fb, kna, 1);                      // buf0'.A1 fp32 loads
        VMW(4);                                  // drain P3's 8
        AWRITE(0, 0, fa);                        // write buf0'.A0 (read next-P1)
        MFMA_Q(1, 1, av, bv);
        LOAD_B(1, 0, bv);
        MFMA_Q(1, 0, av, bv);
        LGKM0(); BAR();
    }
#undef AISSUE
#undef AWRITE
#undef STAGE_B
#undef LOAD_A
#undef LOAD_B
#undef MFMA_Q
#undef BAR
#undef VMW
#undef LGKM0

    // Epilogue: even combined-cols = kv, odd = gate (adjacent lanes).
    // Lane's 4 acc regs = rows q*4..q*4+3 = one r=4 pooling window.
    const bool is_kv = ((h & 1) == 0);
#pragma unroll
    for (int mi = 0; mi < 8; ++mi) {
        const int mbase = m0 + wm * 128 + mi * 16 + q * 4;
        const int wglob = mbase >> 2;
#pragma unroll
        for (int ni = 0; ni < 4; ++ni) {
            f32x4 kv = acc[mi][ni];
            float g0 = __shfl_xor(kv[0], 1);
            float g1 = __shfl_xor(kv[1], 1);
            float g2 = __shfl_xor(kv[2], 1);
            float g3 = __shfl_xor(kv[3], 1);
            if (is_kv) {
                float s = kv[0] * sigm(g0) + kv[1] * sigm(g1) +
                          kv[2] * sigm(g2) + kv[3] * sigm(g3);
                int n = n0 + wn * 64 + ni * 16 + h;   // even
                int o = n >> 1;
                out_pooled[(size_t)wglob * OD + o] = 0.25f * s + ape_mean[o];
            }
        }
    }
}

// ---- in-place RMSNorm over head_dim=512 per token (8192 tokens)
__global__ void rmsnorm_inplace(float* __restrict__ out, const float* __restrict__ nw) {
    int token = blockIdx.x * 4 + (threadIdx.x >> 6);
    int lane  = threadIdx.x & 63;
    float4* p = (float4*)(out + (size_t)token * 512);
    float4 v0 = p[lane * 2], v1 = p[lane * 2 + 1];
    float ss = v0.x * v0.x + v0.y * v0.y + v0.z * v0.z + v0.w * v0.w +
               v1.x * v1.x + v1.y * v1.y + v1.z * v1.z + v1.w * v1.w;
#pragma unroll
    for (int off = 32; off > 0; off >>= 1) ss += __shfl_xor(ss, off);
    float rs = rsqrtf(ss * (1.0f / 512.0f) + 1e-6f);
    const float4* w4 = (const float4*)nw;
    float4 w0 = w4[lane * 2], w1 = w4[lane * 2 + 1];
    float4 r0, r1;
    r0.x = v0.x * rs * w0.x; r0.y = v0.y * rs * w0.y;
    r0.z = v0.z * rs * w0.z; r0.w = v0.w * rs * w0.w;
    r1.x = v1.x * rs * w1.x; r1.y = v1.y * rs * w1.y;
    r1.z = v1.z * rs * w1.z; r1.w = v1.w * rs * w1.w;
    p[lane * 2]     = r0;
    p[lane * 2 + 1] = r1;
}

extern "C" void kernel_launch(void* const* d_in, const int* in_sizes, int n_in,
                              void* d_out, int out_size, void* d_ws, size_t ws_size,
                              hipStream_t stream) {
    const float* x     = (const float*)d_in[0];
    const float* wkv   = (const float*)d_in[1];
    const float* wgate = (const float*)d_in[2];
    const float* ape   = (const float*)d_in[3];
    const float* normw = (const float*)d_in[4];
    float* out = (float*)d_out;

    // ws layout: Wc bf16 [2048][4096] (16 MiB) | ape_mean (4 KiB)
    unsigned short* Wc  = (unsigned short*)d_ws;
    float* ape_mean     = (float*)((char*)d_ws + (size_t)16 * 1024 * 1024);

    prep_weights<<<4096, 256, 0, stream>>>(wkv, wgate, Wc);
    prep_ape<<<4, 256, 0, stream>>>(ape, ape_mean);

    (void)hipFuncSetAttribute(
        reinterpret_cast<const void*>(&gemm_fused_8ph),
        hipFuncAttributeMaxDynamicSharedMemorySize, 131072);
    gemm_fused_8ph<<<(M_TOT / BM) * (N_TOT / BN), 512, 131072, stream>>>(
        x, Wc, ape_mean, out);

    rmsnorm_inplace<<<2048, 256, 0, stream>>>(out, normw);
}

// Round 19
// 377.791 us; speedup vs baseline: 1.0240x; 1.0240x over previous
//
#include <hip/hip_runtime.h>
#include <hip/hip_bf16.h>

// Problem constants (B=4, S=4096, D=4096, r=4, COFF=2, HD=512)
#define D_DIM 4096
#define OD    1024          // COFF*HD combined projection width
#define M_TOT 16384         // B*S
#define N_TOT 2048          // 2*OD (kv/gate interleaved)
#define BM 256
#define BN 256
#define BK 64

#define GLOBAL_AS __attribute__((address_space(1)))
#define LDS_AS    __attribute__((address_space(3)))

typedef __attribute__((ext_vector_type(8))) short          bf16x8;
typedef __attribute__((ext_vector_type(8))) unsigned short u16x8;
typedef __attribute__((ext_vector_type(4))) float          f32x4;

__device__ __forceinline__ unsigned short f2bf(float f) {
    unsigned int u = __float_as_uint(f);
    u = (u + 0x7fffu + ((u >> 16) & 1u)) >> 16;
    return (unsigned short)u;
}

__device__ __forceinline__ float sigm(float x) {
    return 1.0f / (1.0f + __expf(-x));
}

__device__ __forceinline__ void gload16(const void* g, void* l) {
    __builtin_amdgcn_global_load_lds((const GLOBAL_AS void*)g, (LDS_AS void*)l, 16, 0, 0);
}

// ---- prep: interleave wkv/wgate rows into combined bf16 weight [2048][4096]
__global__ void prep_weights(const float* __restrict__ wkv,
                             const float* __restrict__ wgate,
                             unsigned short* __restrict__ Wc) {
    int t  = blockIdx.x * 256 + threadIdx.x;
    int n  = t >> 9;
    int k8 = t & 511;
    const float* src = (n & 1) ? wgate : wkv;
    const float4* s4 = (const float4*)(src + (size_t)(n >> 1) * D_DIM + k8 * 8);
    float4 a = s4[0], b = s4[1];
    u16x8 o;
    o[0] = f2bf(a.x); o[1] = f2bf(a.y); o[2] = f2bf(a.z); o[3] = f2bf(a.w);
    o[4] = f2bf(b.x); o[5] = f2bf(b.y); o[6] = f2bf(b.z); o[7] = f2bf(b.w);
    *(u16x8*)(Wc + (size_t)n * D_DIM + k8 * 8) = o;
}

// ---- prep: ape mean over the 4 window positions
__global__ void prep_ape(const float* __restrict__ ape, float* __restrict__ am) {
    int t = blockIdx.x * 256 + threadIdx.x;
    if (t < OD)
        am[t] = 0.25f * (ape[t] + ape[OD + t] + ape[2 * OD + t] + ape[3 * OD + t]);
}

// =====================================================================
// 256x256 / BK=64 / 8-wave GEMM, r17 interval schedule, A-conversion
// fused (prep_x eliminated) with a 2-INTERVAL A pipeline fixing r18:
//   issue frag Pk -> drained passively by end-Pk+1's VMW -> AWRITE at
//   top of Pk+2 with NO wait attached (data ready a barrier earlier).
// Trace (all write-after-death / read-after-write deadlines verified):
//   fa: issue P1 (buf1.A1@kb1)  write P3   read P4
//   fb: issue P2 (buf0'.A0@kna) write P4   read nP1
//   fa: issue P3 (buf0'.A1@kna) write nP1  read nP2
//   fb: issue P4 (buf1'.A0@knb) write nP2  read nP3
//   B:  gload P1 (buf1@kb1) / P3 (buf0'@kna), drained end-P2 / end-P4
// VMW counts (FIFO): end-P1 VMW(8) [leaves P1's fa+B, drains prev fb];
// end-P2 VMW(4) [leaves fb; drains P1's fa+B -> ready for P3];
// end-P3 VMW(8); end-P4 VMW(4). Issue->drain >= 2 intervals (~1100cy >
// 900cy HBM). Trip-entry invariant: 4 outstanding (P4's fb) = prologue.
// Cross-barrier regs: fa(16)+fb(16)+bv(16) = 48 (proven envelope; r18
// compiled this pressure spill-free). LGKM0+BAR fences every ds_write.
// =====================================================================
extern __shared__ __align__(16) unsigned short smem_u16[];

struct AFrag { float4 v0, v1, v2, v3; };

__global__ __launch_bounds__(512, 2)
void gemm_fused_8ph(const float* __restrict__ X,
                    const unsigned short* __restrict__ Wc,
                    const float* __restrict__ ape_mean,
                    float* __restrict__ out_pooled) {
    unsigned short* Asb[2] = {smem_u16,               smem_u16 + BM * BK};
    unsigned short* Bsb[2] = {smem_u16 + 2 * BM * BK, smem_u16 + 3 * BM * BK};

    const int tid  = threadIdx.x;
    const int lane = tid & 63;
    const int wave = tid >> 6;          // 8 waves: wm = wave>>2 (2), wn = wave&3 (4)
    const int wm   = wave >> 2;
    const int wn   = wave & 3;
    const int h    = lane & 15;
    const int q    = lane >> 4;

    // XCD partition by m: xcd = bid&7 owns m-tiles [xcd*8, xcd*8+8), all 8 n-tiles.
    const int bid = blockIdx.x;
    const int j   = bid >> 3;
    const int m0  = ((bid & 7) * 8 + (j >> 3)) * BM;
    const int n0  = (j & 7) * BN;

    // pre-swizzled source chunk (rule 21 both-sides; verified r3)
    const int sc8 = (lane & 7) ^ ((lane >> 3) & 7);
    const float*          Af = X  + (size_t)(m0 + wave * 8 + (lane >> 3)) * D_DIM + sc8 * 8;
    const unsigned short* Bg = Wc + (size_t)(n0 + (wave & 3) * 8 + (lane >> 3)) * D_DIM + sc8 * 8;
    const int bstripe = wave >> 2;      // waves 0-3: stripes {0,2}; 4-7: {1,3}

    // Precomputed LDS read bases (elements, r13): addr = (W + f*16 + h)*64
    //   + ((ks*32 + q*8) ^ ((h&7)<<3)), frag step f*1024.
    const int xorv = (h & 7) << 3;
    const unsigned aoff0 = (unsigned)((wm * 128 + h) * 64);
    const unsigned boff0 = (unsigned)((wn * 64 + h) * 64);
    const unsigned short* aB[2][2];   // [buf][ks]
    const unsigned short* bB[2][2];
#pragma unroll
    for (int b = 0; b < 2; ++b)
#pragma unroll
        for (int ks = 0; ks < 2; ++ks) {
            const unsigned swz = (unsigned)((ks * 32 + q * 8) ^ xorv);
            aB[b][ks] = Asb[b] + aoff0 + swz;
            bB[b][ks] = Bsb[b] + boff0 + swz;
        }

    // A write targets (linear, identical to the old gload dest)
    unsigned short* AsW0 = Asb[0] + (wave * 8) * BK + lane * 8;
    unsigned short* AsW1 = Asb[1] + (wave * 8) * BK + lane * 8;

#define AISSUE(frag, kofs, half)                                                   \
    do {                                                                           \
        const float* p0_ = Af + (size_t)((half) * 64) * D_DIM + (kofs);            \
        frag.v0 = *(const float4*)(p0_);                                           \
        frag.v1 = *(const float4*)(p0_ + 4);                                       \
        frag.v2 = *(const float4*)(p0_ + (size_t)128 * D_DIM);                     \
        frag.v3 = *(const float4*)(p0_ + (size_t)128 * D_DIM + 4);                 \
    } while (0)

#define AWRITE(buf, half, frag)                                                    \
    do {                                                                           \
        u16x8 w0_, w1_;                                                            \
        w0_[0] = f2bf(frag.v0.x); w0_[1] = f2bf(frag.v0.y);                        \
        w0_[2] = f2bf(frag.v0.z); w0_[3] = f2bf(frag.v0.w);                        \
        w0_[4] = f2bf(frag.v1.x); w0_[5] = f2bf(frag.v1.y);                        \
        w0_[6] = f2bf(frag.v1.z); w0_[7] = f2bf(frag.v1.w);                        \
        w1_[0] = f2bf(frag.v2.x); w1_[1] = f2bf(frag.v2.y);                        \
        w1_[2] = f2bf(frag.v2.z); w1_[3] = f2bf(frag.v2.w);                        \
        w1_[4] = f2bf(frag.v3.x); w1_[5] = f2bf(frag.v3.y);                        \
        w1_[6] = f2bf(frag.v3.z); w1_[7] = f2bf(frag.v3.w);                        \
        unsigned short* d_ = ((buf) ? AsW1 : AsW0) + (half) * 64 * BK;             \
        *(u16x8*)(d_)             = w0_;                                           \
        *(u16x8*)(d_ + 128 * BK)  = w1_;                                           \
    } while (0)

#define STAGE_B(buf, qb, kofs)                                                     \
    do {                                                                           \
        const int r0_ = (qb) * 32 + bstripe * 64;                                  \
        const int r1_ = (qb) * 32 + (2 + bstripe) * 64;                            \
        gload16(Bg + (size_t)r0_ * D_DIM + (kofs),                                 \
                Bsb[buf] + (r0_ + (wave & 3) * 8) * BK);                           \
        gload16(Bg + (size_t)r1_ * D_DIM + (kofs),                                 \
                Bsb[buf] + (r1_ + (wave & 3) * 8) * BK);                           \
    } while (0)

#define LOAD_A(buf, qa, dst)                                                       \
    do {                                                                           \
        _Pragma("unroll")                                                          \
        for (int mi = 0; mi < 4; ++mi)                                             \
            _Pragma("unroll")                                                      \
            for (int ks = 0; ks < 2; ++ks)                                         \
                dst[mi][ks] = *(const bf16x8*)(aB[buf][ks] +                       \
                              ((qa) * 4 + mi) * 1024);                             \
    } while (0)

#define LOAD_B(buf, qb, dst)                                                       \
    do {                                                                           \
        _Pragma("unroll")                                                          \
        for (int ni = 0; ni < 2; ++ni)                                             \
            _Pragma("unroll")                                                      \
            for (int ks = 0; ks < 2; ++ks)                                         \
                dst[ni][ks] = *(const bf16x8*)(bB[buf][ks] +                       \
                              ((qb) * 2 + ni) * 1024);                             \
    } while (0)

#define MFMA_Q(qa, qb, asrc, bsrc)                                                 \
    do {                                                                           \
        __builtin_amdgcn_s_setprio(1);                                             \
        _Pragma("unroll")                                                          \
        for (int mi = 0; mi < 4; ++mi)                                             \
            _Pragma("unroll")                                                      \
            for (int ni = 0; ni < 2; ++ni)                                         \
                _Pragma("unroll")                                                  \
                for (int ks = 0; ks < 2; ++ks)                                     \
                    acc[(qa) * 4 + mi][(qb) * 2 + ni] =                            \
                        __builtin_amdgcn_mfma_f32_16x16x32_bf16(                   \
                            asrc[mi][ks], bsrc[ni][ks],                            \
                            acc[(qa) * 4 + mi][(qb) * 2 + ni], 0, 0, 0);           \
        __builtin_amdgcn_s_setprio(0);                                             \
    } while (0)

#define BAR()   __builtin_amdgcn_s_barrier()
#define VMW(n)  asm volatile("s_waitcnt vmcnt(" #n ")" ::: "memory")
#define LGKM0() asm volatile("s_waitcnt lgkmcnt(0)" ::: "memory")

    f32x4 acc[8][4];
    const f32x4 z = {0.f, 0.f, 0.f, 0.f};
#pragma unroll
    for (int i = 0; i < 8; ++i)
#pragma unroll
        for (int jj = 0; jj < 4; ++jj) acc[i][jj] = z;

    AFrag fa, fb;

    // ---- prologue: buf0.A0 loaded+written; buf0.B gloads; fa=buf0.A1@0
    // (written P1), fb=buf1.A0@64 (written P2). VMW(4) leaves only fb's 4
    // outstanding = steady trip-entry invariant; fa and B complete.
    AISSUE(fa, 0, 0);
    VMW(0);
    AWRITE(0, 0, fa);
    STAGE_B(0, 0, 0); STAGE_B(0, 1, 0);
    AISSUE(fa, 0, 1);
    AISSUE(fb, 64, 0);
    VMW(4);
    LGKM0();
    BAR();

    for (int kt2 = 0; kt2 < D_DIM; kt2 += 2 * BK) {
        const int kb1 = kt2 + BK;                // buf1 tile this trip (<= 4032)
        const int kna = (kt2 + 2 * BK) & 4095;   // next buf0 tile (wraps: dead)
        const int knb = (kt2 + 3 * BK) & 4095;   // next buf1 tile (wraps: dead)
        bf16x8 av[4][2], bv[2][2];

        // ---- P1: read buf0 Q(0,0),Q(0,1) ----
        LOAD_A(0, 0, av); LOAD_B(0, 0, bv);
        AWRITE(0, 1, fa);                        // buf0.A1 (drained end prev-P4)
        AISSUE(fa, kb1, 1);                      // buf1.A1 fp32 loads
        STAGE_B(1, 0, kb1); STAGE_B(1, 1, kb1);  // buf1 B0,B1 gloads
        MFMA_Q(0, 0, av, bv);
        LOAD_B(0, 1, bv);
        MFMA_Q(0, 1, av, bv);
        VMW(8);                                  // drain prev-P4's fb (for P2 write)
        LGKM0(); BAR();

        // ---- P2: read buf0 Q(1,1),Q(1,0) ----
        LOAD_A(0, 1, av);
        AWRITE(1, 0, fb);                        // buf1.A0 (drained end-P1)
        AISSUE(fb, kna, 0);                      // buf0'.A0 fp32 loads
        MFMA_Q(1, 1, av, bv);
        LOAD_B(0, 0, bv);
        MFMA_Q(1, 0, av, bv);
        VMW(4);                                  // drain P1's fa + buf1.B (for P3)
        LGKM0(); BAR();

        // ---- P3: read buf1 Q(0,0),Q(0,1) ----
        LOAD_A(1, 0, av); LOAD_B(1, 0, bv);
        AWRITE(1, 1, fa);                        // buf1.A1 (drained end-P2)
        AISSUE(fa, kna, 1);                      // buf0'.A1 fp32 loads
        STAGE_B(0, 0, kna); STAGE_B(0, 1, kna);  // buf0' B0,B1 gloads
        MFMA_Q(0, 0, av, bv);
        LOAD_B(1, 1, bv);
        MFMA_Q(0, 1, av, bv);
        VMW(8);                                  // drain P2's fb (for P4 write)
        LGKM0(); BAR();

        // ---- P4: read buf1 Q(1,1),Q(1,0) ----
        LOAD_A(1, 1, av);
        AWRITE(0, 0, fb);                        // buf0'.A0 (drained end-P3)
        AISSUE(fb, knb, 0);                      // buf1'.A0 fp32 loads
        MFMA_Q(1, 1, av, bv);
        LOAD_B(1, 0, bv);
        MFMA_Q(1, 0, av, bv);
        VMW(4);                                  // drain P3's fa + buf0'.B
        LGKM0(); BAR();
    }
#undef AISSUE
#undef AWRITE
#undef STAGE_B
#undef LOAD_A
#undef LOAD_B
#undef MFMA_Q
#undef BAR
#undef VMW
#undef LGKM0

    // Epilogue: even combined-cols = kv, odd = gate (adjacent lanes).
    // Lane's 4 acc regs = rows q*4..q*4+3 = one r=4 pooling window.
    const bool is_kv = ((h & 1) == 0);
#pragma unroll
    for (int mi = 0; mi < 8; ++mi) {
        const int mbase = m0 + wm * 128 + mi * 16 + q * 4;
        const int wglob = mbase >> 2;
#pragma unroll
        for (int ni = 0; ni < 4; ++ni) {
            f32x4 kv = acc[mi][ni];
            float g0 = __shfl_xor(kv[0], 1);
            float g1 = __shfl_xor(kv[1], 1);
            float g2 = __shfl_xor(kv[2], 1);
            float g3 = __shfl_xor(kv[3], 1);
            if (is_kv) {
                float s = kv[0] * sigm(g0) + kv[1] * sigm(g1) +
                          kv[2] * sigm(g2) + kv[3] * sigm(g3);
                int n = n0 + wn * 64 + ni * 16 + h;   // even
                int o = n >> 1;
                out_pooled[(size_t)wglob * OD + o] = 0.25f * s + ape_mean[o];
            }
        }
    }
}

// ---- in-place RMSNorm over head_dim=512 per token (8192 tokens)
__global__ void rmsnorm_inplace(float* __restrict__ out, const float* __restrict__ nw) {
    int token = blockIdx.x * 4 + (threadIdx.x >> 6);
    int lane  = threadIdx.x & 63;
    float4* p = (float4*)(out + (size_t)token * 512);
    float4 v0 = p[lane * 2], v1 = p[lane * 2 + 1];
    float ss = v0.x * v0.x + v0.y * v0.y + v0.z * v0.z + v0.w * v0.w +
               v1.x * v1.x + v1.y * v1.y + v1.z * v1.z + v1.w * v1.w;
#pragma unroll
    for (int off = 32; off > 0; off >>= 1) ss += __shfl_xor(ss, off);
    float rs = rsqrtf(ss * (1.0f / 512.0f) + 1e-6f);
    const float4* w4 = (const float4*)nw;
    float4 w0 = w4[lane * 2], w1 = w4[lane * 2 + 1];
    float4 r0, r1;
    r0.x = v0.x * rs * w0.x; r0.y = v0.y * rs * w0.y;
    r0.z = v0.z * rs * w0.z; r0.w = v0.w * rs * w0.w;
    r1.x = v1.x * rs * w1.x; r1.y = v1.y * rs * w1.y;
    r1.z = v1.z * rs * w1.z; r1.w = v1.w * rs * w1.w;
    p[lane * 2]     = r0;
    p[lane * 2 + 1] = r1;
}

extern "C" void kernel_launch(void* const* d_in, const int* in_sizes, int n_in,
                              void* d_out, int out_size, void* d_ws, size_t ws_size,
                              hipStream_t stream) {
    const float* x     = (const float*)d_in[0];
    const float* wkv   = (const float*)d_in[1];
    const float* wgate = (const float*)d_in[2];
    const float* ape   = (const float*)d_in[3];
    const float* normw = (const float*)d_in[4];
    float* out = (float*)d_out;

    // ws layout: Wc bf16 [2048][4096] (16 MiB) | ape_mean (4 KiB)
    unsigned short* Wc  = (unsigned short*)d_ws;
    float* ape_mean     = (float*)((char*)d_ws + (size_t)16 * 1024 * 1024);

    prep_weights<<<4096, 256, 0, stream>>>(wkv, wgate, Wc);
    prep_ape<<<4, 256, 0, stream>>>(ape, ape_mean);

    (void)hipFuncSetAttribute(
        reinterpret_cast<const void*>(&gemm_fused_8ph),
        hipFuncAttributeMaxDynamicSharedMemorySize, 131072);
    gemm_fused_8ph<<<(M_TOT / BM) * (N_TOT / BN), 512, 131072, stream>>>(
        x, Wc, ape_mean, out);

    rmsnorm_inplace<<<2048, 256, 0, stream>>>(out, normw);
}

// Round 20
// 302.505 us; speedup vs baseline: 1.2789x; 1.2489x over previous
//
#include <hip/hip_runtime.h>
#include <hip/hip_bf16.h>

// Problem constants (B=4, S=4096, D=4096, r=4, COFF=2, HD=512)
#define D_DIM 4096
#define OD    1024          // COFF*HD combined projection width
#define M_TOT 16384         // B*S
#define N_TOT 2048          // 2*OD (kv/gate interleaved)
#define BM 256
#define BN 256
#define BK 64

#define GLOBAL_AS __attribute__((address_space(1)))
#define LDS_AS    __attribute__((address_space(3)))

typedef __attribute__((ext_vector_type(8))) short          bf16x8;
typedef __attribute__((ext_vector_type(8))) unsigned short u16x8;
typedef __attribute__((ext_vector_type(4))) float          f32x4;

__device__ __forceinline__ unsigned short f2bf(float f) {
    unsigned int u = __float_as_uint(f);
    u = (u + 0x7fffu + ((u >> 16) & 1u)) >> 16;
    return (unsigned short)u;
}

__device__ __forceinline__ float sigm(float x) {
    return 1.0f / (1.0f + __expf(-x));
}

__device__ __forceinline__ void gload16(const void* g, void* l) {
    __builtin_amdgcn_global_load_lds((const GLOBAL_AS void*)g, (LDS_AS void*)l, 16, 0, 0);
}

// ---- prep: interleave wkv/wgate rows into combined bf16 weight [2048][4096]
__global__ void prep_weights(const float* __restrict__ wkv,
                             const float* __restrict__ wgate,
                             unsigned short* __restrict__ Wc) {
    int t  = blockIdx.x * 256 + threadIdx.x;
    int n  = t >> 9;
    int k8 = t & 511;
    const float* src = (n & 1) ? wgate : wkv;
    const float4* s4 = (const float4*)(src + (size_t)(n >> 1) * D_DIM + k8 * 8);
    float4 a = s4[0], b = s4[1];
    u16x8 o;
    o[0] = f2bf(a.x); o[1] = f2bf(a.y); o[2] = f2bf(a.z); o[3] = f2bf(a.w);
    o[4] = f2bf(b.x); o[5] = f2bf(b.y); o[6] = f2bf(b.z); o[7] = f2bf(b.w);
    *(u16x8*)(Wc + (size_t)n * D_DIM + k8 * 8) = o;
}

// ---- prep: x fp32 -> bf16
__global__ void prep_x(const float* __restrict__ x, unsigned short* __restrict__ xb) {
    size_t t = (size_t)blockIdx.x * 256 + threadIdx.x;
    const float4* s = (const float4*)(x + t * 8);
    float4 a = s[0], b = s[1];
    u16x8 o;
    o[0] = f2bf(a.x); o[1] = f2bf(a.y); o[2] = f2bf(a.z); o[3] = f2bf(a.w);
    o[4] = f2bf(b.x); o[5] = f2bf(b.y); o[6] = f2bf(b.z); o[7] = f2bf(b.w);
    *(u16x8*)(xb + t * 8) = o;
}

// ---- prep: ape mean over the 4 window positions
__global__ void prep_ape(const float* __restrict__ ape, float* __restrict__ am) {
    int t = blockIdx.x * 256 + threadIdx.x;
    if (t < OD)
        am[t] = 0.25f * (ape[t] + ape[OD + t] + ape[2 * OD + t] + ape[3 * OD + t]);
}

// =====================================================================
// FINAL (r17-verified): 256x256 / BK=64 / 8-wave GEMM, 4 merged barrier
// intervals per 2-K-tile trip, each = [reads|stage|2 MFMA clusters|
// (vmcnt)|BAR]. Operand-chain read order (0,0)->(0,1)->(1,1)->(1,0),
// 28 ds_read_b128/K-tile, B0 (4-read group) re-read. Stage map:
//   P1: buf1{A1,B0}@kb1   (old contents died prev-P4)
//   P2: buf0'{A0,B1}@kna  (died P1)  + vmcnt(4) -> all 8 buf1 done
//   P3: buf0'{A1,B0}@kna  (died P2)
//   P4: buf1''{A0,B1}@knb (died P3)  + vmcnt(4) -> all 8 buf0' done
// FIFO invariant: 4 outstanding at trip entry. Both operands staged by
// global_load_lds with pre-swizzled source (rule 21 both-sides, 0 bank
// conflicts measured); precomputed swizzled LDS read bases; per-phase
// live operands <= 48 VGPR (no spill, WRITE_SIZE = pure output).
// Measured r17: GEMM 233.7us, MfmaUtil 54.7%, 1156 TF (46% dense peak).
// =====================================================================
extern __shared__ __align__(16) unsigned short smem_u16[];

__global__ __launch_bounds__(512, 2)
void gemm_fused_8ph(const unsigned short* __restrict__ A,
                    const unsigned short* __restrict__ Wc,
                    const float* __restrict__ ape_mean,
                    float* __restrict__ out_pooled) {
    unsigned short* Asb[2] = {smem_u16,               smem_u16 + BM * BK};
    unsigned short* Bsb[2] = {smem_u16 + 2 * BM * BK, smem_u16 + 3 * BM * BK};

    const int tid  = threadIdx.x;
    const int lane = tid & 63;
    const int wave = tid >> 6;          // 8 waves: wm = wave>>2 (2), wn = wave&3 (4)
    const int wm   = wave >> 2;
    const int wn   = wave & 3;
    const int h    = lane & 15;
    const int q    = lane >> 4;

    // XCD partition by m: xcd = bid&7 owns m-tiles [xcd*8, xcd*8+8), all 8 n-tiles.
    const int bid = blockIdx.x;
    const int j   = bid >> 3;
    const int m0  = ((bid & 7) * 8 + (j >> 3)) * BM;
    const int n0  = (j & 7) * BN;

    // staging: pre-swizzled source chunk (rule 21 both-sides; verified r3)
    const int sc8 = (lane & 7) ^ ((lane >> 3) & 7);
    const unsigned short* Ag = A  + (size_t)(m0 + wave * 8 + (lane >> 3)) * D_DIM + sc8 * 8;
    const unsigned short* Bg = Wc + (size_t)(n0 + (wave & 3) * 8 + (lane >> 3)) * D_DIM + sc8 * 8;
    const int bstripe = wave >> 2;      // waves 0-3: stripes {0,2}; 4-7: {1,3}

    // Precomputed LDS read bases (elements, r13): addr = (W + f*16 + h)*64
    //   + ((ks*32 + q*8) ^ ((h&7)<<3)), frag step f*1024.
    const int xorv = (h & 7) << 3;
    const unsigned aoff0 = (unsigned)((wm * 128 + h) * 64);
    const unsigned boff0 = (unsigned)((wn * 64 + h) * 64);
    const unsigned short* aB[2][2];   // [buf][ks]
    const unsigned short* bB[2][2];
#pragma unroll
    for (int b = 0; b < 2; ++b)
#pragma unroll
        for (int ks = 0; ks < 2; ++ks) {
            const unsigned swz = (unsigned)((ks * 32 + q * 8) ^ xorv);
            aB[b][ks] = Asb[b] + aoff0 + swz;
            bB[b][ks] = Bsb[b] + boff0 + swz;
        }

#define STAGE_A(buf, half, kofs)                                                   \
    do {                                                                           \
        gload16(Ag + (size_t)((half) * 64) * D_DIM + (kofs),                       \
                Asb[buf] + ((half) * 64 + wave * 8) * BK);                         \
        gload16(Ag + (size_t)((half) * 64 + 128) * D_DIM + (kofs),                 \
                Asb[buf] + ((half) * 64 + 128 + wave * 8) * BK);                   \
    } while (0)

#define STAGE_B(buf, qb, kofs)                                                     \
    do {                                                                           \
        const int r0_ = (qb) * 32 + bstripe * 64;                                  \
        const int r1_ = (qb) * 32 + (2 + bstripe) * 64;                            \
        gload16(Bg + (size_t)r0_ * D_DIM + (kofs),                                 \
                Bsb[buf] + (r0_ + (wave & 3) * 8) * BK);                           \
        gload16(Bg + (size_t)r1_ * D_DIM + (kofs),                                 \
                Bsb[buf] + (r1_ + (wave & 3) * 8) * BK);                           \
    } while (0)

#define LOAD_A(buf, qa, dst)                                                       \
    do {                                                                           \
        _Pragma("unroll")                                                          \
        for (int mi = 0; mi < 4; ++mi)                                             \
            _Pragma("unroll")                                                      \
            for (int ks = 0; ks < 2; ++ks)                                         \
                dst[mi][ks] = *(const bf16x8*)(aB[buf][ks] +                       \
                              ((qa) * 4 + mi) * 1024);                             \
    } while (0)

#define LOAD_B(buf, qb, dst)                                                       \
    do {                                                                           \
        _Pragma("unroll")                                                          \
        for (int ni = 0; ni < 2; ++ni)                                             \
            _Pragma("unroll")                                                      \
            for (int ks = 0; ks < 2; ++ks)                                         \
                dst[ni][ks] = *(const bf16x8*)(bB[buf][ks] +                       \
                              ((qb) * 2 + ni) * 1024);                             \
    } while (0)

#define MFMA_Q(qa, qb, asrc, bsrc)                                                 \
    do {                                                                           \
        __builtin_amdgcn_s_setprio(1);                                             \
        _Pragma("unroll")                                                          \
        for (int mi = 0; mi < 4; ++mi)                                             \
            _Pragma("unroll")                                                      \
            for (int ni = 0; ni < 2; ++ni)                                         \
                _Pragma("unroll")                                                  \
                for (int ks = 0; ks < 2; ++ks)                                     \
                    acc[(qa) * 4 + mi][(qb) * 2 + ni] =                            \
                        __builtin_amdgcn_mfma_f32_16x16x32_bf16(                   \
                            asrc[mi][ks], bsrc[ni][ks],                            \
                            acc[(qa) * 4 + mi][(qb) * 2 + ni], 0, 0, 0);           \
        __builtin_amdgcn_s_setprio(0);                                             \
    } while (0)

#define BAR() __builtin_amdgcn_s_barrier()
#define VMW4() asm volatile("s_waitcnt vmcnt(4)" ::: "memory")

    f32x4 acc[8][4];
    const f32x4 z = {0.f, 0.f, 0.f, 0.f};
#pragma unroll
    for (int i = 0; i < 8; ++i)
#pragma unroll
        for (int jj = 0; jj < 4; ++jj) acc[i][jj] = z;

    // prologue: buf0 <- T0 full (8 loads), buf1 <- T1 {A0,B1} (4 loads).
    // vmcnt(4): buf0's 8 complete; buf1's 4 outstanding = steady invariant.
    STAGE_A(0, 0, 0); STAGE_A(0, 1, 0); STAGE_B(0, 0, 0); STAGE_B(0, 1, 0);
    STAGE_A(1, 0, 64); STAGE_B(1, 1, 64);
    VMW4();
    BAR();

    for (int kt2 = 0; kt2 < D_DIM; kt2 += 2 * BK) {
        const int kb1 = kt2 + BK;                // buf1 tile this trip (<= 4032)
        const int kna = (kt2 + 2 * BK) & 4095;   // next buf0 tile (wraps: dead)
        const int knb = (kt2 + 3 * BK) & 4095;   // next buf1 tile (wraps: dead)
        bf16x8 av[4][2], bv[2][2];

        // ---- P1 = {ph1, ph2}: read buf0 (0,0) then (0,1) ----
        LOAD_A(0, 0, av); LOAD_B(0, 0, bv);
        STAGE_A(1, 1, kb1); STAGE_B(1, 0, kb1);  // buf1 A1,B0 (died prev-P4)
        MFMA_Q(0, 0, av, bv);
        LOAD_B(0, 1, bv);
        MFMA_Q(0, 1, av, bv);
        BAR();
        // ---- P2 = {ph3, ph4}: read buf0 (1,1) then (1,0) ----
        LOAD_A(0, 1, av);
        MFMA_Q(1, 1, av, bv);
        LOAD_B(0, 0, bv);
        STAGE_A(0, 0, kna); STAGE_B(0, 1, kna);  // buf0' A0,B1 (died P1)
        MFMA_Q(1, 0, av, bv);
        VMW4();                                  // all 8 buf1(kb1) loads done
        BAR();
        // ---- P3 = {ph5, ph6}: read buf1 (0,0) then (0,1) ----
        LOAD_A(1, 0, av); LOAD_B(1, 0, bv);
        STAGE_A(0, 1, kna); STAGE_B(0, 0, kna);  // buf0' A1,B0 (died P2)
        MFMA_Q(0, 0, av, bv);
        LOAD_B(1, 1, bv);
        MFMA_Q(0, 1, av, bv);
        BAR();
        // ---- P4 = {ph7, ph8}: read buf1 (1,1) then (1,0) ----
        LOAD_A(1, 1, av);
        MFMA_Q(1, 1, av, bv);
        LOAD_B(1, 0, bv);
        STAGE_A(1, 0, knb); STAGE_B(1, 1, knb);  // buf1'' A0,B1 (died P3)
        MFMA_Q(1, 0, av, bv);
        VMW4();                                  // all 8 buf0'(kna) loads done
        BAR();
    }
#undef STAGE_A
#undef STAGE_B
#undef LOAD_A
#undef LOAD_B
#undef MFMA_Q
#undef BAR
#undef VMW4

    // Epilogue: even combined-cols = kv, odd = gate (adjacent lanes).
    // Lane's 4 acc regs = rows q*4..q*4+3 = one r=4 pooling window.
    const bool is_kv = ((h & 1) == 0);
#pragma unroll
    for (int mi = 0; mi < 8; ++mi) {
        const int mbase = m0 + wm * 128 + mi * 16 + q * 4;
        const int wglob = mbase >> 2;
#pragma unroll
        for (int ni = 0; ni < 4; ++ni) {
            f32x4 kv = acc[mi][ni];
            float g0 = __shfl_xor(kv[0], 1);
            float g1 = __shfl_xor(kv[1], 1);
            float g2 = __shfl_xor(kv[2], 1);
            float g3 = __shfl_xor(kv[3], 1);
            if (is_kv) {
                float s = kv[0] * sigm(g0) + kv[1] * sigm(g1) +
                          kv[2] * sigm(g2) + kv[3] * sigm(g3);
                int n = n0 + wn * 64 + ni * 16 + h;   // even
                int o = n >> 1;
                out_pooled[(size_t)wglob * OD + o] = 0.25f * s + ape_mean[o];
            }
        }
    }
}

// ---- fallback (ws too small for xb): fp32 A + reg staging + XOR swizzle (r3)
__global__ __launch_bounds__(256)
void gemm_fused_f32(const float* __restrict__ Aptr,
                    const unsigned short* __restrict__ Wc,
                    const float* __restrict__ ape_mean,
                    float* __restrict__ out_pooled) {
    __shared__ __align__(16) unsigned short As[128 * BK];
    __shared__ __align__(16) unsigned short Bs[128 * BK];
    const int tid  = threadIdx.x;
    const int lane = tid & 63;
    const int wave = tid >> 6;
    const int wr   = wave >> 1;
    const int wc   = wave & 1;
    const int n0   = blockIdx.x * 128;
    const int m0   = blockIdx.y * 128;
    const int h    = lane & 15;
    const int q    = lane >> 4;

    f32x4 acc[4][4];
    const f32x4 z = {0.f, 0.f, 0.f, 0.f};
#pragma unroll
    for (int i = 0; i < 4; ++i)
#pragma unroll
        for (int jj = 0; jj < 4; ++jj) acc[i][jj] = z;

    for (int kt = 0; kt < D_DIM; kt += BK) {
#pragma unroll
        for (int i = 0; i < 4; ++i) {
            int chunk = tid + i * 256;
            int row = chunk >> 3, c8 = chunk & 7;
            int dst = (row * BK + c8 * 8) ^ ((row & 7) << 3);
            const float4* s = (const float4*)(Aptr + (size_t)(m0 + row) * D_DIM + kt + c8 * 8);
            float4 a = s[0], b = s[1];
            u16x8 o;
            o[0] = f2bf(a.x); o[1] = f2bf(a.y); o[2] = f2bf(a.z); o[3] = f2bf(a.w);
            o[4] = f2bf(b.x); o[5] = f2bf(b.y); o[6] = f2bf(b.z); o[7] = f2bf(b.w);
            *(u16x8*)&As[dst] = o;
        }
#pragma unroll
        for (int i = 0; i < 4; ++i) {
            int chunk = tid + i * 256;
            int row = chunk >> 3, c8 = chunk & 7;
            int dst = (row * BK + c8 * 8) ^ ((row & 7) << 3);
            *(u16x8*)&Bs[dst] =
                *(const u16x8*)(Wc + (size_t)(n0 + row) * D_DIM + kt + c8 * 8);
        }
        __syncthreads();
#pragma unroll
        for (int ks = 0; ks < 2; ++ks) {
            const int kb = ks * 32 + q * 8;
            bf16x8 af[4], bfr[4];
#pragma unroll
            for (int am = 0; am < 4; ++am) {
                int row = wr * 64 + am * 16 + h;
                af[am] = *(const bf16x8*)&As[(row * BK + kb) ^ ((row & 7) << 3)];
            }
#pragma unroll
            for (int bn = 0; bn < 4; ++bn) {
                int row = wc * 64 + bn * 16 + h;
                bfr[bn] = *(const bf16x8*)&Bs[(row * BK + kb) ^ ((row & 7) << 3)];
            }
#pragma unroll
            for (int am = 0; am < 4; ++am)
#pragma unroll
                for (int bn = 0; bn < 4; ++bn)
                    acc[am][bn] = __builtin_amdgcn_mfma_f32_16x16x32_bf16(
                        af[am], bfr[bn], acc[am][bn], 0, 0, 0);
        }
        __syncthreads();
    }
    const bool is_kv = ((h & 1) == 0);
#pragma unroll
    for (int am = 0; am < 4; ++am) {
        const int mbase = m0 + wr * 64 + am * 16 + q * 4;
        const int wglob = mbase >> 2;
#pragma unroll
        for (int bn = 0; bn < 4; ++bn) {
            f32x4 kv = acc[am][bn];
            float g0 = __shfl_xor(kv[0], 1);
            float g1 = __shfl_xor(kv[1], 1);
            float g2 = __shfl_xor(kv[2], 1);
            float g3 = __shfl_xor(kv[3], 1);
            if (is_kv) {
                float s = kv[0] * sigm(g0) + kv[1] * sigm(g1) +
                          kv[2] * sigm(g2) + kv[3] * sigm(g3);
                int n = n0 + wc * 64 + bn * 16 + h;
                int o = n >> 1;
                out_pooled[(size_t)wglob * OD + o] = 0.25f * s + ape_mean[o];
            }
        }
    }
}

// ---- in-place RMSNorm over head_dim=512 per token (8192 tokens)
__global__ void rmsnorm_inplace(float* __restrict__ out, const float* __restrict__ nw) {
    int token = blockIdx.x * 4 + (threadIdx.x >> 6);
    int lane  = threadIdx.x & 63;
    float4* p = (float4*)(out + (size_t)token * 512);
    float4 v0 = p[lane * 2], v1 = p[lane * 2 + 1];
    float ss = v0.x * v0.x + v0.y * v0.y + v0.z * v0.z + v0.w * v0.w +
               v1.x * v1.x + v1.y * v1.y + v1.z * v1.z + v1.w * v1.w;
#pragma unroll
    for (int off = 32; off > 0; off >>= 1) ss += __shfl_xor(ss, off);
    float rs = rsqrtf(ss * (1.0f / 512.0f) + 1e-6f);
    const float4* w4 = (const float4*)nw;
    float4 w0 = w4[lane * 2], w1 = w4[lane * 2 + 1];
    float4 r0, r1;
    r0.x = v0.x * rs * w0.x; r0.y = v0.y * rs * w0.y;
    r0.z = v0.z * rs * w0.z; r0.w = v0.w * rs * w0.w;
    r1.x = v1.x * rs * w1.x; r1.y = v1.y * rs * w1.y;
    r1.z = v1.z * rs * w1.z; r1.w = v1.w * rs * w1.w;
    p[lane * 2]     = r0;
    p[lane * 2 + 1] = r1;
}

extern "C" void kernel_launch(void* const* d_in, const int* in_sizes, int n_in,
                              void* d_out, int out_size, void* d_ws, size_t ws_size,
                              hipStream_t stream) {
    const float* x     = (const float*)d_in[0];
    const float* wkv   = (const float*)d_in[1];
    const float* wgate = (const float*)d_in[2];
    const float* ape   = (const float*)d_in[3];
    const float* normw = (const float*)d_in[4];
    float* out = (float*)d_out;

    unsigned short* Wc  = (unsigned short*)d_ws;
    float* ape_mean     = (float*)((char*)d_ws + (size_t)16 * 1024 * 1024);
    unsigned short* xb  = (unsigned short*)((char*)d_ws + (size_t)16 * 1024 * 1024 + 65536);
    const size_t need_xb = (size_t)16 * 1024 * 1024 + 65536 + (size_t)M_TOT * D_DIM * 2;
    const bool use_xb = (ws_size >= need_xb);

    prep_weights<<<4096, 256, 0, stream>>>(wkv, wgate, Wc);
    prep_ape<<<4, 256, 0, stream>>>(ape, ape_mean);

    if (use_xb) {
        prep_x<<<32768, 256, 0, stream>>>(x, xb);
        (void)hipFuncSetAttribute(
            reinterpret_cast<const void*>(&gemm_fused_8ph),
            hipFuncAttributeMaxDynamicSharedMemorySize, 131072);
        gemm_fused_8ph<<<(M_TOT / BM) * (N_TOT / BN), 512, 131072, stream>>>(
            xb, Wc, ape_mean, out);
    } else {
        gemm_fused_f32<<<dim3(N_TOT / 128, M_TOT / 128), 256, 0, stream>>>(
            x, Wc, ape_mean, out);
    }

    rmsnorm_inplace<<<2048, 256, 0, stream>>>(out, normw);
}